// Round 1
// baseline (138.274 us; speedup 1.0000x reference)
//
#include <hip/hip_runtime.h>
#include <hip/hip_cooperative_groups.h>

namespace cg = cooperative_groups;

#define BSZ   2
#define NBOX  6300
#define NATTR 85
#define NCLS  80
#define CAP   256      // per-(img,class) cap; count ~ Binom(6300,1/160): mean 39, sd 6.3
#define NBLK  512      // cooperative grid: __launch_bounds__(256,2) -> 2 blocks/CU -> 512 co-resident
#define NWAVES (NBLK * 4)

typedef unsigned long long ull;

static __device__ __forceinline__ ull mask_for(int rem) {
  if (rem <= 0) return 0ull;
  if (rem >= 64) return ~0ull;
  return (1ull << rem) - 1ull;
}

// Fused prep + NMS in one cooperative launch.
//
// Phase 1 (all 512 blocks, 2048 waves, wave-strided over 12600 boxes):
//   One wave per box. Lanes load the 85 attrs, butterfly-reduce max/argmax over
//   class scores (attrs 5..84, first-index tiebreak = jnp.argmax). Lane 0 writes
//   the FINAL output row (real row if valid, zeros otherwise) and pushes valid
//   boxes into the per-(img,cls) candidate list via atomicAdd. List order is
//   arbitrary: the NMS rank is a stable total order on (score desc, box idx asc)
//   computed by pairwise comparison, so no sorted insertion is needed.
//
// grid.sync() (cooperative) = device-scope barrier + release/acquire, making the
// out rows and lists visible across XCDs.
//
// Phase 2 (blocks 0..159, one per (img,cls)): greedy per-class NMS, exactly
// equivalent to the ref's global greedy loop (suppression requires same_cls;
// invalid boxes never act). Kept rows are already final in out; this phase only
// ZEROES suppressed rows. Fast path (k<=64, always on this data): whole NMS in
// wave-0 registers via shfl/ds_permute/ballot. Generic LDS path kept for k>64.
__global__ __launch_bounds__(256, 2) void fused_kernel(
    const float* __restrict__ x,
    float* __restrict__ out,
    int* __restrict__ cnt,     // [BSZ*NCLS], zeroed by hipMemsetAsync
    int* __restrict__ list) {  // [BSZ*NCLS][CAP]
  int lane = threadIdx.x & 63;
  int gw   = (blockIdx.x * 256 + (int)threadIdx.x) >> 6;   // global wave id, 0..2047

  // ---------------- Phase 1: prep ----------------
  for (int box = gw; box < BSZ * NBOX; box += NWAVES) {
    const float* p = x + (long)box * NATTR;
    float r0 = p[lane];                                    // attrs 0..63
    float r1 = (lane < NATTR - 64) ? p[64 + lane] : -1.0f; // attrs 64..84

    float c0 = (lane >= 5) ? r0 : -1.0f;
    float v; int vi;
    if (r1 > c0) { v = r1; vi = 64 + lane; }   // equal -> keep lower index c0
    else         { v = c0; vi = lane; }

    for (int off = 32; off > 0; off >>= 1) {   // butterfly max-argmax
      float ov = __shfl_xor(v, off);
      int   oi = __shfl_xor(vi, off);
      if (ov > v || (ov == v && oi < vi)) { v = ov; vi = oi; }
    }

    float cx  = __shfl(r0, 0), cy = __shfl(r0, 1);
    float w   = __shfl(r0, 2), h  = __shfl(r0, 3);
    float obj = __shfl(r0, 4);
    bool valid = (obj > 0.5f) && (v > 0.3f);
    int  img   = box >= NBOX ? 1 : 0;
    int  bi    = box - img * NBOX;
    int  cls   = vi - 5;

    if (lane == 0) {
      float4 a, b;
      if (valid) {
        float hw = w * 0.5f, hh = h * 0.5f;    // exact halving; fma-safe
        a = make_float4((float)img, cx - hw, cy - hh, cx + hw);
        b = make_float4(cy + hh, obj, v, (float)cls);
        int li = img * NCLS + cls;
        int slot = atomicAdd(&cnt[li], 1);     // ~39 pushes/counter: no contention
        if (slot < CAP) list[li * CAP + slot] = bi;
      } else {
        a = make_float4(0.f, 0.f, 0.f, 0.f);
        b = a;
      }
      float4* o = (float4*)(out + (long)box * 8);
      o[0] = a; o[1] = b;
    }
  }

  cg::this_grid().sync();

  // ---------------- Phase 2: NMS ----------------
  int bc = blockIdx.x;
  if (bc >= BSZ * NCLS) return;

  __shared__ int   sbi[CAP];
  // fallback-only arrays (k > 64)
  __shared__ float ssc[CAP];
  __shared__ float px1[CAP], py1[CAP], px2[CAP], py2[CAP];
  __shared__ int   pbi[CAP];

  int img = bc / NCLS;
  int t   = threadIdx.x;
  int w   = t >> 6;

  int total = cnt[bc];
  int k = total < CAP ? total : CAP;
  if (k == 0) return;                  // uniform

  for (int j = t; j < k; j += 256) sbi[j] = list[bc * CAP + j];
  __syncthreads();

  if (k <= 64) {
    // ================== register fast path (wave 0 only) ==================
    if (w == 0) {
      int j = lane;
      float x1 = 0.f, y1 = 0.f, x2 = 0.f, y2 = 0.f, sc = 0.f;
      int bi = 0;
      if (j < k) {
        bi = sbi[j];
        const float4* o = (const float4*)(out + ((long)img * NBOX + bi) * 8);
        float4 a = o[0], b = o[1];
        x1 = a.y; y1 = a.z; x2 = a.w; y2 = b.x; sc = b.y;
      }
      // rank = stable argsort(-score, tiebreak: box index asc).
      // All 64 lanes run the loop (no divergence -> shfl well-defined);
      // j>=k lanes get identity rank j (>= k, no collision: sc=0 there).
      int rank = 0;
      for (int i = 0; i < k; i++) {
        float si  = __shfl(sc, i);
        int   bii = __shfl(bi, i);
        rank += (si > sc) || (si == sc && bii < bi);
      }
      if (j >= k) rank = j;

      // scatter to rank order: after this, lane index == rank.
      int r4 = rank << 2;
      x1 = __int_as_float(__builtin_amdgcn_ds_permute(r4, __float_as_int(x1)));
      y1 = __int_as_float(__builtin_amdgcn_ds_permute(r4, __float_as_int(y1)));
      x2 = __int_as_float(__builtin_amdgcn_ds_permute(r4, __float_as_int(x2)));
      y2 = __int_as_float(__builtin_amdgcn_ds_permute(r4, __float_as_int(y2)));
      bi = __builtin_amdgcn_ds_permute(r4, bi);

      float ar = (x2 - x1) * (y2 - y1);   // ref area expression

      // greedy: kept rank r suppresses later ranks with IoU >= 0.4
      ull keep = mask_for(k);
      for (int r = 0; r < k - 1; r++) {
        if (!((keep >> r) & 1ull)) continue;   // uniform skip
        float X1 = __shfl(x1, r), Y1 = __shfl(y1, r);
        float X2 = __shfl(x2, r), Y2 = __shfl(y2, r);
        float AR = __shfl(ar, r);
        float iw = fminf(X2, x2) - fmaxf(X1, x1);
        float ih = fminf(Y2, y2) - fmaxf(Y1, y1);
        iw = fmaxf(iw, 0.0f); ih = fmaxf(ih, 0.0f);
        float inter = iw * ih;
        float iou = inter / (AR + ar - inter + 1e-16f);  // ref assoc + eps
        keep &= ~__ballot(iou >= 0.4f && lane > r);
      }

      // zero only the suppressed rows (kept rows already final from prep)
      if (lane < k && !((keep >> lane) & 1ull)) {
        float4 z = make_float4(0.f, 0.f, 0.f, 0.f);
        float4* o = (float4*)(out + ((long)img * NBOX + bi) * 8);
        o[0] = z; o[1] = z;
      }
    }
    return;
  }

  // ====================== generic LDS fallback (k > 64) ======================
  float bx1 = 0, by1 = 0, bx2 = 0, by2 = 0, bobj = 0;
  int   bidx = 0;
  if (t < k) {
    bidx = sbi[t];
    const float4* o = (const float4*)(out + ((long)img * NBOX + bidx) * 8);
    float4 a = o[0], b = o[1];
    bx1 = a.y; by1 = a.z; bx2 = a.w; by2 = b.x; bobj = b.y;
    ssc[t] = bobj;
  }
  __syncthreads();

  if (t < k) {
    // stable rank by (score desc, box idx asc) — independent of list order
    int rank = 0;
    for (int j = 0; j < k; j++) {
      float sj = ssc[j];
      rank += (sj > bobj) || (sj == bobj && sbi[j] < bidx);
    }
    px1[rank] = bx1; py1[rank] = by1;
    px2[rank] = bx2; py2[rank] = by2;
    pbi[rank] = bidx;
  }
  __syncthreads();

  if (w == 0) {
    float mx1[4], my1[4], mx2[4], my2[4], mar[4];
    int   mbi[4];
#pragma unroll
    for (int s = 0; s < 4; s++) {
      int e = s * 64 + lane;
      if (e < k) {
        mx1[s] = px1[e]; my1[s] = py1[e];
        mx2[s] = px2[e]; my2[s] = py2[e];
        mbi[s] = pbi[e];
        mar[s] = (mx2[s] - mx1[s]) * (my2[s] - my1[s]);
      } else {
        mx1[s] = 0; my1[s] = 0; mx2[s] = 0; my2[s] = 0; mar[s] = 0; mbi[s] = 0;
      }
    }
    ull km0 = mask_for(k);
    ull km1 = mask_for(k - 64);
    ull km2 = mask_for(k - 128);
    ull km3 = mask_for(k - 192);

    for (int r = 0; r < k - 1; r++) {
      ull cur = (r < 64) ? km0 : (r < 128) ? km1 : (r < 192) ? km2 : km3;
      if (!((cur >> (r & 63)) & 1ull)) continue;
      float X1 = px1[r], Y1 = py1[r], X2 = px2[r], Y2 = py2[r];
      float ar = (X2 - X1) * (Y2 - Y1);
      {
        int e = lane;
        float iw = fminf(X2, mx2[0]) - fmaxf(X1, mx1[0]);
        float ih = fminf(Y2, my2[0]) - fmaxf(Y1, my1[0]);
        iw = fmaxf(iw, 0.0f); ih = fmaxf(ih, 0.0f);
        float inter = iw * ih;
        float iou = inter / (ar + mar[0] - inter + 1e-16f);
        km0 &= ~__ballot(iou >= 0.4f && e > r && e < k);
      }
      if (k > 64) {
        int e = 64 + lane;
        float iw = fminf(X2, mx2[1]) - fmaxf(X1, mx1[1]);
        float ih = fminf(Y2, my2[1]) - fmaxf(Y1, my1[1]);
        iw = fmaxf(iw, 0.0f); ih = fmaxf(ih, 0.0f);
        float inter = iw * ih;
        float iou = inter / (ar + mar[1] - inter + 1e-16f);
        km1 &= ~__ballot(iou >= 0.4f && e > r && e < k);
      }
      if (k > 128) {
        int e = 128 + lane;
        float iw = fminf(X2, mx2[2]) - fmaxf(X1, mx1[2]);
        float ih = fminf(Y2, my2[2]) - fmaxf(Y1, my1[2]);
        iw = fmaxf(iw, 0.0f); ih = fmaxf(ih, 0.0f);
        float inter = iw * ih;
        float iou = inter / (ar + mar[2] - inter + 1e-16f);
        km2 &= ~__ballot(iou >= 0.4f && e > r && e < k);
      }
      if (k > 192) {
        int e = 192 + lane;
        float iw = fminf(X2, mx2[3]) - fmaxf(X1, mx1[3]);
        float ih = fminf(Y2, my2[3]) - fmaxf(Y1, my1[3]);
        iw = fmaxf(iw, 0.0f); ih = fmaxf(ih, 0.0f);
        float inter = iw * ih;
        float iou = inter / (ar + mar[3] - inter + 1e-16f);
        km3 &= ~__ballot(iou >= 0.4f && e > r && e < k);
      }
    }

    float4 z = make_float4(0.f, 0.f, 0.f, 0.f);
#pragma unroll
    for (int s = 0; s < 4; s++) {
      ull kms = (s == 0) ? km0 : (s == 1) ? km1 : (s == 2) ? km2 : km3;
      int e = s * 64 + lane;
      if (e < k && !((kms >> lane) & 1ull)) {
        float4* o = (float4*)(out + ((long)img * NBOX + mbi[s]) * 8);
        o[0] = z; o[1] = z;
      }
    }
  }
}

extern "C" void kernel_launch(void* const* d_in, const int* in_sizes, int n_in,
                              void* d_out, int out_size, void* d_ws, size_t ws_size,
                              hipStream_t stream) {
  const float* x = (const float*)d_in[0];
  float* out = (float*)d_out;
  int* cnt  = (int*)d_ws;           // [BSZ*NCLS] = 160 ints
  int* list = (int*)d_ws + 256;     // [BSZ*NCLS][CAP] ints, 1-KiB aligned offset

  hipMemsetAsync(cnt, 0, BSZ * NCLS * sizeof(int), stream);  // 640 B, capture-safe

  void* args[] = { (void*)&x, (void*)&out, (void*)&cnt, (void*)&list };
  hipLaunchCooperativeKernel((void*)fused_kernel, dim3(NBLK), dim3(256),
                             args, 0, stream);
}

// Round 2
// 107.879 us; speedup vs baseline: 1.2818x; 1.2818x over previous
//
#include <hip/hip_runtime.h>

#define BSZ   2
#define NBOX  6300
#define NATTR 85
#define NCLS  80
#define CAP   256      // per-(img,class) cap; count ~ Binom(6300,1/160): mean 39, sd 6.3
#define TPB   512

typedef unsigned long long ull;

static __device__ __forceinline__ ull mask_for(int rem) {
  if (rem <= 0) return 0ull;
  if (rem >= 64) return ~0ull;
  return (1ull << rem) - 1ull;
}

// ONE kernel, one block per (img, cls). No workspace, no memset, no grid sync
// (round-1 post-mortem: cg grid.sync costs ~65 us on this grid -- never again).
//
// Each block scans its image thread-per-box (input is 4.28 MB total -> L2/L3
// resident; the 160x redundant scan is cache traffic, not HBM). For each box it
// recomputes the ref semantics exactly:
//   conf = obj > 0.5; masked scores = conf ? scores : 0
//   cls_idx = argmax(masked scores)  (first-index tiebreak; all-zero -> 0)
//   valid = conf && max_score > 0.3
// The block OWNS every box with cls_idx == its class. Owners write zero rows
// for invalid boxes immediately; valid boxes go to an LDS candidate list
// (block-local atomicAdd; order-independent because NMS rank is the stable
// total order (obj desc, box idx asc)). Then greedy per-class NMS -- exactly
// equivalent to the ref's global greedy loop (suppression requires same_cls;
// invalid boxes never act). Kept rows written real, suppressed written zero.
// Every output row is written exactly once by its unique owner.
__global__ __launch_bounds__(TPB) void nms_fused(
    const float* __restrict__ x,
    float* __restrict__ out) {
  __shared__ int   scnt;
  __shared__ float sx1[CAP], sy1[CAP], sx2[CAP], sy2[CAP];
  __shared__ float sob[CAP], smx[CAP];
  __shared__ int   sbi[CAP];
  // fallback-only (k > 64), rank-ordered
  __shared__ float px1[CAP], py1[CAP], px2[CAP], py2[CAP];
  __shared__ float pob[CAP], pmx[CAP];
  __shared__ int   pbi[CAP];

  int bc   = blockIdx.x;
  int img  = bc / NCLS;
  int cls  = bc - img * NCLS;
  int t    = threadIdx.x;
  int lane = t & 63;
  int w    = t >> 6;

  if (t == 0) scnt = 0;
  __syncthreads();

  const float* xb = x + (long)img * NBOX * NATTR;
  float*       ob = out + (long)img * NBOX * 8;

  // ---- scan: thread-per-box, strided. Loads are independent scalar dwords
  // (row base is only 4B-aligned), fully pipelined, L2/L3-hit after warm-up.
  for (int b = t; b < NBOX; b += TPB) {
    const float* p = xb + (long)b * NATTR;
    float cx  = p[0], cy = p[1], ww = p[2], hh = p[3], obj = p[4];
    float best = p[5];
    int   ci   = 0;
#pragma unroll
    for (int c = 1; c < NCLS; ++c) {
      float s = p[5 + c];
      if (s > best) { best = s; ci = c; }   // strict > keeps first index (jnp.argmax)
    }
    bool conf  = obj > 0.5f;
    bool valid = conf && (best > 0.3f);
    int  owner = conf ? ci : 0;             // masked scores all 0 -> argmax = 0

    if (owner == cls) {
      if (valid) {
        int slot = atomicAdd(&scnt, 1);     // LDS atomic, ~39 pushes/block
        if (slot < CAP) {
          float hw = ww * 0.5f, hh2 = hh * 0.5f;  // exact halving; fma-safe
          sx1[slot] = cx - hw;  sy1[slot] = cy - hh2;
          sx2[slot] = cx + hw;  sy2[slot] = cy + hh2;
          sob[slot] = obj;      smx[slot] = best;
          sbi[slot] = b;
        }
      } else {
        float4 z = make_float4(0.f, 0.f, 0.f, 0.f);
        float4* o = (float4*)(ob + (long)b * 8);
        o[0] = z; o[1] = z;
      }
    }
  }
  __syncthreads();

  int k = scnt < CAP ? scnt : CAP;
  if (k == 0) return;                  // uniform

  if (k <= 64) {
    // ================== register fast path (wave 0 only) ==================
    if (w == 0) {
      int j = lane;
      float x1 = 0.f, y1 = 0.f, x2 = 0.f, y2 = 0.f, sc = 0.f, mx = 0.f;
      int bi = 0;
      if (j < k) {
        x1 = sx1[j]; y1 = sy1[j]; x2 = sx2[j]; y2 = sy2[j];
        sc = sob[j]; mx = smx[j]; bi = sbi[j];
      }
      // rank = stable argsort(-obj, tiebreak: box index asc) -- independent of
      // the atomicAdd arrival order. All 64 lanes run the loop (no divergence);
      // j>=k lanes get identity rank j (>= k, no collision: sc=0 there).
      int rank = 0;
      for (int i = 0; i < k; i++) {
        float si  = __shfl(sc, i);
        int   bii = __shfl(bi, i);
        rank += (si > sc) || (si == sc && bii < bi);
      }
      if (j >= k) rank = j;

      // scatter to rank order: after this, lane index == rank.
      int r4 = rank << 2;
      x1 = __int_as_float(__builtin_amdgcn_ds_permute(r4, __float_as_int(x1)));
      y1 = __int_as_float(__builtin_amdgcn_ds_permute(r4, __float_as_int(y1)));
      x2 = __int_as_float(__builtin_amdgcn_ds_permute(r4, __float_as_int(x2)));
      y2 = __int_as_float(__builtin_amdgcn_ds_permute(r4, __float_as_int(y2)));
      sc = __int_as_float(__builtin_amdgcn_ds_permute(r4, __float_as_int(sc)));
      mx = __int_as_float(__builtin_amdgcn_ds_permute(r4, __float_as_int(mx)));
      bi = __builtin_amdgcn_ds_permute(r4, bi);

      float ar = (x2 - x1) * (y2 - y1);   // ref area expression

      // greedy: kept rank r suppresses later ranks with IoU >= 0.4
      ull keep = mask_for(k);
      for (int r = 0; r < k - 1; r++) {
        if (!((keep >> r) & 1ull)) continue;   // uniform skip
        float X1 = __shfl(x1, r), Y1 = __shfl(y1, r);
        float X2 = __shfl(x2, r), Y2 = __shfl(y2, r);
        float AR = __shfl(ar, r);
        float iw = fminf(X2, x2) - fmaxf(X1, x1);
        float ih = fminf(Y2, y2) - fmaxf(Y1, y1);
        iw = fmaxf(iw, 0.0f); ih = fmaxf(ih, 0.0f);
        float inter = iw * ih;
        float iou = inter / (AR + ar - inter + 1e-16f);  // ref assoc + eps
        keep &= ~__ballot(iou >= 0.4f && lane > r);
      }

      if (lane < k) {
        float4 a, b4;
        if ((keep >> lane) & 1ull) {
          a  = make_float4((float)img, x1, y1, x2);
          b4 = make_float4(y2, sc, mx, (float)cls);
        } else {
          a  = make_float4(0.f, 0.f, 0.f, 0.f);
          b4 = a;
        }
        float4* o = (float4*)(ob + (long)bi * 8);
        o[0] = a; o[1] = b4;
      }
    }
    return;
  }

  // ====================== generic LDS fallback (k > 64) ======================
  if (t < k) {
    float bx1 = sx1[t], by1 = sy1[t], bx2 = sx2[t], by2 = sy2[t];
    float bob = sob[t], bmx = smx[t];
    int   bidx = sbi[t];
    int rank = 0;
    for (int j = 0; j < k; j++) {
      float sj = sob[j];
      rank += (sj > bob) || (sj == bob && sbi[j] < bidx);
    }
    px1[rank] = bx1; py1[rank] = by1;
    px2[rank] = bx2; py2[rank] = by2;
    pob[rank] = bob; pmx[rank] = bmx;
    pbi[rank] = bidx;
  }
  __syncthreads();

  if (w == 0) {
    float mx1[4], my1[4], mx2[4], my2[4], mar[4], mob[4], mmx[4];
    int   mbi[4];
#pragma unroll
    for (int s = 0; s < 4; s++) {
      int e = s * 64 + lane;
      if (e < k) {
        mx1[s] = px1[e]; my1[s] = py1[e];
        mx2[s] = px2[e]; my2[s] = py2[e];
        mob[s] = pob[e]; mmx[s] = pmx[e];
        mbi[s] = pbi[e];
        mar[s] = (mx2[s] - mx1[s]) * (my2[s] - my1[s]);
      } else {
        mx1[s] = 0; my1[s] = 0; mx2[s] = 0; my2[s] = 0;
        mar[s] = 0; mob[s] = 0; mmx[s] = 0; mbi[s] = 0;
      }
    }
    ull km0 = mask_for(k);
    ull km1 = mask_for(k - 64);
    ull km2 = mask_for(k - 128);
    ull km3 = mask_for(k - 192);

    for (int r = 0; r < k - 1; r++) {
      ull cur = (r < 64) ? km0 : (r < 128) ? km1 : (r < 192) ? km2 : km3;
      if (!((cur >> (r & 63)) & 1ull)) continue;
      float X1 = px1[r], Y1 = py1[r], X2 = px2[r], Y2 = py2[r];
      float ar = (X2 - X1) * (Y2 - Y1);
      {
        int e = lane;
        float iw = fminf(X2, mx2[0]) - fmaxf(X1, mx1[0]);
        float ih = fminf(Y2, my2[0]) - fmaxf(Y1, my1[0]);
        iw = fmaxf(iw, 0.0f); ih = fmaxf(ih, 0.0f);
        float inter = iw * ih;
        float iou = inter / (ar + mar[0] - inter + 1e-16f);
        km0 &= ~__ballot(iou >= 0.4f && e > r && e < k);
      }
      if (k > 64) {
        int e = 64 + lane;
        float iw = fminf(X2, mx2[1]) - fmaxf(X1, mx1[1]);
        float ih = fminf(Y2, my2[1]) - fmaxf(Y1, my1[1]);
        iw = fmaxf(iw, 0.0f); ih = fmaxf(ih, 0.0f);
        float inter = iw * ih;
        float iou = inter / (ar + mar[1] - inter + 1e-16f);
        km1 &= ~__ballot(iou >= 0.4f && e > r && e < k);
      }
      if (k > 128) {
        int e = 128 + lane;
        float iw = fminf(X2, mx2[2]) - fmaxf(X1, mx1[2]);
        float ih = fminf(Y2, my2[2]) - fmaxf(Y1, my1[2]);
        iw = fmaxf(iw, 0.0f); ih = fmaxf(ih, 0.0f);
        float inter = iw * ih;
        float iou = inter / (ar + mar[2] - inter + 1e-16f);
        km2 &= ~__ballot(iou >= 0.4f && e > r && e < k);
      }
      if (k > 192) {
        int e = 192 + lane;
        float iw = fminf(X2, mx2[3]) - fmaxf(X1, mx1[3]);
        float ih = fminf(Y2, my2[3]) - fmaxf(Y1, my1[3]);
        iw = fmaxf(iw, 0.0f); ih = fmaxf(ih, 0.0f);
        float inter = iw * ih;
        float iou = inter / (ar + mar[3] - inter + 1e-16f);
        km3 &= ~__ballot(iou >= 0.4f && e > r && e < k);
      }
    }

#pragma unroll
    for (int s = 0; s < 4; s++) {
      ull kms = (s == 0) ? km0 : (s == 1) ? km1 : (s == 2) ? km2 : km3;
      int e = s * 64 + lane;
      if (e < k) {
        float4 a, b4;
        if ((kms >> lane) & 1ull) {
          a  = make_float4((float)img, mx1[s], my1[s], mx2[s]);
          b4 = make_float4(my2[s], mob[s], mmx[s], (float)cls);
        } else {
          a  = make_float4(0.f, 0.f, 0.f, 0.f);
          b4 = a;
        }
        float4* o = (float4*)(ob + (long)mbi[s] * 8);
        o[0] = a; o[1] = b4;
      }
    }
  }
}

extern "C" void kernel_launch(void* const* d_in, const int* in_sizes, int n_in,
                              void* d_out, int out_size, void* d_ws, size_t ws_size,
                              hipStream_t stream) {
  const float* x = (const float*)d_in[0];
  float* out = (float*)d_out;
  nms_fused<<<BSZ * NCLS, TPB, 0, stream>>>(x, out);
}

// Round 3
// 98.154 us; speedup vs baseline: 1.4087x; 1.0991x over previous
//
#include <hip/hip_runtime.h>

#define BSZ   2
#define NBOX  6300
#define NATTR 85
#define NCLS  80
#define CAP   256      // per-(img,class) cap; count ~ Binom(6300,1/160): mean 39, sd 6.3
#define TPB   512
#define NW    8        // waves per block
#define NBLK  (BSZ * NCLS)          // 160 blocks == one per (img,cls)
#define GWAVES (NBLK * NW)          // 1280 waves for phase 1
#define CHUNK 790      // 8*790 = 6320 >= 6300 (per-wave scan chunk)
#define WCAP  128      // per-wave candidate cap (expect ~5; 128 is >>12 sigma)

typedef unsigned long long ull;

static __device__ __forceinline__ ull mask_for(int rem) {
  if (rem <= 0) return 0ull;
  if (rem >= 64) return ~0ull;
  return (1ull << rem) - 1ull;
}

// Per-block-distinct arrival magic. A waiter requires ALL 160 distinct values
// to be present, so no uniform/byte-repeat ws poison pattern can spuriously
// release the barrier (it could match at most one flag). The harness re-poisons
// ws every replay (fills observed per-iteration in R0/R1 dispatch streams),
// which wipes the flags between replays.
static __device__ __forceinline__ int magic_of(int b) {
  return (int)(0xA53C9E1Du ^ ((unsigned)b * 0x9E3779B9u));
}

// ONE kernel, 160 blocks x 512 threads (all co-resident: <1 block/CU -> the
// custom barrier cannot deadlock).
//
// Phase 1 (R0-verified prep, grid-strided wave-per-box): lanes load the 85
// attrs coalesced, butterfly max/argmax over class scores (first-index
// tiebreak = jnp.argmax). Lane 0 writes the FINAL out row (real if valid,
// zeros otherwise) and vcls[box] = valid ? cls : -1.
//
// Custom grid barrier (NOT cg::grid.sync, which measured ~65 us in R1):
// release fence + per-block magic flag store; wave 0 polls all 160 flags with
// agent-scope atomic loads + s_sleep backoff; acquire fence.
//
// Phase 2 (R0-verified per-class NMS): ballot-compaction scan of vcls
// (8 waves x 790 chunk), then register fast-path greedy NMS (k<=64, always on
// this data) on wave 0 -- rank by (obj desc, box idx asc), ds_permute scatter,
// serial greedy ballot loop. Only suppressed rows get zeroed (kept rows are
// already final from phase 1). LDS fallback retained for k>64.
__global__ __launch_bounds__(TPB, 2) void nms_one(
    const float* __restrict__ x,
    float* __restrict__ out,
    int* __restrict__ ws) {
  int* vcls  = ws;          // [BSZ*NBOX] = 12600 ints
  int* flags = ws + 12800;  // [NBLK] ints

  __shared__ int   wlist[NW][WCAP];
  __shared__ int   wcnt[NW];
  __shared__ int   sbi[CAP];
  // fallback-only arrays (k > 64)
  __shared__ float ssc[CAP];
  __shared__ float px1[CAP], py1[CAP], px2[CAP], py2[CAP];
  __shared__ int   pbi[CAP];

  int t    = threadIdx.x;
  int lane = t & 63;
  int w    = t >> 6;
  int bid  = blockIdx.x;

  // ---------------- Phase 1: prep (wave-per-box, coalesced) ----------------
  for (int box = bid * NW + w; box < BSZ * NBOX; box += GWAVES) {
    const float* p = x + (long)box * NATTR;
    float r0 = p[lane];                                    // attrs 0..63
    float r1 = (lane < NATTR - 64) ? p[64 + lane] : -1.0f; // attrs 64..84

    float c0 = (lane >= 5) ? r0 : -1.0f;
    float v; int vi;
    if (r1 > c0) { v = r1; vi = 64 + lane; }   // equal -> keep lower index c0
    else         { v = c0; vi = lane; }

    for (int off = 32; off > 0; off >>= 1) {   // butterfly max-argmax
      float ov = __shfl_xor(v, off);
      int   oi = __shfl_xor(vi, off);
      if (ov > v || (ov == v && oi < vi)) { v = ov; vi = oi; }
    }

    float cx  = __shfl(r0, 0), cy = __shfl(r0, 1);
    float ww  = __shfl(r0, 2), hh = __shfl(r0, 3);
    float obj = __shfl(r0, 4);
    bool valid = (obj > 0.5f) && (v > 0.3f);
    int  img   = box >= NBOX ? 1 : 0;
    int  cls   = vi - 5;

    if (lane == 0) {
      vcls[box] = valid ? cls : -1;
      float4 a, b;
      if (valid) {
        float hw = ww * 0.5f, hh2 = hh * 0.5f;  // exact halving; fma-safe
        a = make_float4((float)img, cx - hw, cy - hh2, cx + hw);
        b = make_float4(cy + hh2, obj, v, (float)cls);
      } else {
        a = make_float4(0.f, 0.f, 0.f, 0.f);
        b = a;
      }
      float4* o = (float4*)(out + (long)box * 8);
      o[0] = a; o[1] = b;
    }
  }

  // ---------------- Custom grid barrier ----------------
  __syncthreads();
  __threadfence();                      // release vcls + out rows (device scope)
  if (t == 0)
    __hip_atomic_store(&flags[bid], magic_of(bid),
                       __ATOMIC_RELEASE, __HIP_MEMORY_SCOPE_AGENT);
  if (w == 0) {
    int m0 = magic_of(lane);
    int m1 = magic_of(64 + lane);
    int m2 = (lane < 32) ? magic_of(128 + lane) : 0;
    for (;;) {
      int f0 = __hip_atomic_load(&flags[lane],
                                 __ATOMIC_RELAXED, __HIP_MEMORY_SCOPE_AGENT);
      int f1 = __hip_atomic_load(&flags[64 + lane],
                                 __ATOMIC_RELAXED, __HIP_MEMORY_SCOPE_AGENT);
      int f2 = (lane < 32)
                 ? __hip_atomic_load(&flags[128 + lane],
                                     __ATOMIC_RELAXED, __HIP_MEMORY_SCOPE_AGENT)
                 : 0;
      bool c = (f0 == m0) && (f1 == m1) && (lane >= 32 || f2 == m2);
      if (__all(c)) break;
      __builtin_amdgcn_s_sleep(8);
    }
    __threadfence();                    // acquire (invalidate stale cache lines)
  }
  __syncthreads();                      // releases waves 1..7 after acquire

  // ---------------- Phase 2: per-(img,cls) NMS ----------------
  int img = bid / NCLS;
  int cls = bid - img * NCLS;
  const int* v = vcls + img * NBOX;

  // ---- scan: 8 waves x 790-chunk ballot compaction ----
  int base = w * CHUNK;
  int vals[13];
#pragma unroll
  for (int i = 0; i < 13; i++) {
    int local = i * 64 + lane;
    int idx   = base + local;
    vals[i] = (local < CHUNK && idx < NBOX) ? v[idx] : -1;
  }
  int cnt = 0;
  ull lt = (1ull << lane) - 1ull;
#pragma unroll
  for (int i = 0; i < 13; i++) {
    bool match = (vals[i] == cls);
    ull  m = __ballot(match);
    if (match) {
      int pos = cnt + __popcll(m & lt);
      if (pos < WCAP) wlist[w][pos] = base + i * 64 + lane;
    }
    cnt += __popcll(m);
  }
  if (lane == 0) wcnt[w] = cnt < WCAP ? cnt : WCAP;
  __syncthreads();

  int off = 0, total = 0;
  for (int j = 0; j < NW; j++) {
    int c = wcnt[j];
    if (j < w) off += c;
    total += c;
  }
  int k = total < CAP ? total : CAP;
  if (k == 0) return;                  // uniform

  for (int j = lane; j < wcnt[w]; j += 64) {
    int d = off + j;
    if (d < CAP) sbi[d] = wlist[w][j];  // ascending box-index order
  }
  __syncthreads();

  if (k <= 64) {
    // ================== register fast path (wave 0 only) ==================
    if (w == 0) {
      int j = lane;
      float x1 = 0.f, y1 = 0.f, x2 = 0.f, y2 = 0.f, sc = 0.f;
      int bi = 0;
      if (j < k) {
        bi = sbi[j];
        const float4* o = (const float4*)(out + ((long)img * NBOX + bi) * 8);
        float4 a = o[0], b = o[1];
        x1 = a.y; y1 = a.z; x2 = a.w; y2 = b.x; sc = b.y;
      }
      // rank = stable argsort(-obj, tiebreak: box index asc).
      // All 64 lanes run the loop (no divergence -> shfl well-defined);
      // j>=k lanes get identity rank j (>= k, no collision: sc=0 there).
      int rank = 0;
      for (int i = 0; i < k; i++) {
        float si  = __shfl(sc, i);
        int   bii = __shfl(bi, i);
        rank += (si > sc) || (si == sc && bii < bi);
      }
      if (j >= k) rank = j;

      // scatter to rank order: after this, lane index == rank.
      int r4 = rank << 2;
      x1 = __int_as_float(__builtin_amdgcn_ds_permute(r4, __float_as_int(x1)));
      y1 = __int_as_float(__builtin_amdgcn_ds_permute(r4, __float_as_int(y1)));
      x2 = __int_as_float(__builtin_amdgcn_ds_permute(r4, __float_as_int(x2)));
      y2 = __int_as_float(__builtin_amdgcn_ds_permute(r4, __float_as_int(y2)));
      bi = __builtin_amdgcn_ds_permute(r4, bi);

      float ar = (x2 - x1) * (y2 - y1);   // ref area expression

      // greedy: kept rank r suppresses later ranks with IoU >= 0.4
      ull keep = mask_for(k);
      for (int r = 0; r < k - 1; r++) {
        if (!((keep >> r) & 1ull)) continue;   // uniform skip
        float X1 = __shfl(x1, r), Y1 = __shfl(y1, r);
        float X2 = __shfl(x2, r), Y2 = __shfl(y2, r);
        float AR = __shfl(ar, r);
        float iw = fminf(X2, x2) - fmaxf(X1, x1);
        float ih = fminf(Y2, y2) - fmaxf(Y1, y1);
        iw = fmaxf(iw, 0.0f); ih = fmaxf(ih, 0.0f);
        float inter = iw * ih;
        float iou = inter / (AR + ar - inter + 1e-16f);  // ref assoc + eps
        keep &= ~__ballot(iou >= 0.4f && lane > r);
      }

      // zero only the suppressed rows (kept rows already final from phase 1)
      if (lane < k && !((keep >> lane) & 1ull)) {
        float4 z = make_float4(0.f, 0.f, 0.f, 0.f);
        float4* o = (float4*)(out + ((long)img * NBOX + bi) * 8);
        o[0] = z; o[1] = z;
      }
    }
    return;
  }

  // ====================== generic LDS fallback (k > 64) ======================
  float bx1 = 0, by1 = 0, bx2 = 0, by2 = 0, bobj = 0;
  int   bidx = 0;
  if (t < k) {
    bidx = sbi[t];
    const float4* o = (const float4*)(out + ((long)img * NBOX + bidx) * 8);
    float4 a = o[0], b = o[1];
    bx1 = a.y; by1 = a.z; bx2 = a.w; by2 = b.x; bobj = b.y;
    ssc[t] = bobj;
  }
  __syncthreads();

  if (t < k) {
    int rank = 0;
    for (int j = 0; j < k; j++) {
      float sj = ssc[j];
      rank += (sj > bobj) || (sj == bobj && sbi[j] < bidx);
    }
    px1[rank] = bx1; py1[rank] = by1;
    px2[rank] = bx2; py2[rank] = by2;
    pbi[rank] = bidx;
  }
  __syncthreads();

  if (w == 0) {
    float mx1[4], my1[4], mx2[4], my2[4], mar[4];
    int   mbi[4];
#pragma unroll
    for (int s = 0; s < 4; s++) {
      int e = s * 64 + lane;
      if (e < k) {
        mx1[s] = px1[e]; my1[s] = py1[e];
        mx2[s] = px2[e]; my2[s] = py2[e];
        mbi[s] = pbi[e];
        mar[s] = (mx2[s] - mx1[s]) * (my2[s] - my1[s]);
      } else {
        mx1[s] = 0; my1[s] = 0; mx2[s] = 0; my2[s] = 0; mar[s] = 0; mbi[s] = 0;
      }
    }
    ull km0 = mask_for(k);
    ull km1 = mask_for(k - 64);
    ull km2 = mask_for(k - 128);
    ull km3 = mask_for(k - 192);

    for (int r = 0; r < k - 1; r++) {
      ull cur = (r < 64) ? km0 : (r < 128) ? km1 : (r < 192) ? km2 : km3;
      if (!((cur >> (r & 63)) & 1ull)) continue;
      float X1 = px1[r], Y1 = py1[r], X2 = px2[r], Y2 = py2[r];
      float ar = (X2 - X1) * (Y2 - Y1);
      {
        int e = lane;
        float iw = fminf(X2, mx2[0]) - fmaxf(X1, mx1[0]);
        float ih = fminf(Y2, my2[0]) - fmaxf(Y1, my1[0]);
        iw = fmaxf(iw, 0.0f); ih = fmaxf(ih, 0.0f);
        float inter = iw * ih;
        float iou = inter / (ar + mar[0] - inter + 1e-16f);
        km0 &= ~__ballot(iou >= 0.4f && e > r && e < k);
      }
      if (k > 64) {
        int e = 64 + lane;
        float iw = fminf(X2, mx2[1]) - fmaxf(X1, mx1[1]);
        float ih = fminf(Y2, my2[1]) - fmaxf(Y1, my1[1]);
        iw = fmaxf(iw, 0.0f); ih = fmaxf(ih, 0.0f);
        float inter = iw * ih;
        float iou = inter / (ar + mar[1] - inter + 1e-16f);
        km1 &= ~__ballot(iou >= 0.4f && e > r && e < k);
      }
      if (k > 128) {
        int e = 128 + lane;
        float iw = fminf(X2, mx2[2]) - fmaxf(X1, mx1[2]);
        float ih = fminf(Y2, my2[2]) - fmaxf(Y1, my1[2]);
        iw = fmaxf(iw, 0.0f); ih = fmaxf(ih, 0.0f);
        float inter = iw * ih;
        float iou = inter / (ar + mar[2] - inter + 1e-16f);
        km2 &= ~__ballot(iou >= 0.4f && e > r && e < k);
      }
      if (k > 192) {
        int e = 192 + lane;
        float iw = fminf(X2, mx2[3]) - fmaxf(X1, mx1[3]);
        float ih = fminf(Y2, my2[3]) - fmaxf(Y1, my1[3]);
        iw = fmaxf(iw, 0.0f); ih = fmaxf(ih, 0.0f);
        float inter = iw * ih;
        float iou = inter / (ar + mar[3] - inter + 1e-16f);
        km3 &= ~__ballot(iou >= 0.4f && e > r && e < k);
      }
    }

    float4 z = make_float4(0.f, 0.f, 0.f, 0.f);
#pragma unroll
    for (int s = 0; s < 4; s++) {
      ull kms = (s == 0) ? km0 : (s == 1) ? km1 : (s == 2) ? km2 : km3;
      int e = s * 64 + lane;
      if (e < k && !((kms >> lane) & 1ull)) {
        float4* o = (float4*)(out + ((long)img * NBOX + mbi[s]) * 8);
        o[0] = z; o[1] = z;
      }
    }
  }
}

extern "C" void kernel_launch(void* const* d_in, const int* in_sizes, int n_in,
                              void* d_out, int out_size, void* d_ws, size_t ws_size,
                              hipStream_t stream) {
  const float* x = (const float*)d_in[0];
  float* out = (float*)d_out;
  int* ws = (int*)d_ws;   // vcls[12600] + flags[160]
  nms_one<<<NBLK, TPB, 0, stream>>>(x, out, ws);
}

// Round 4
// 68.642 us; speedup vs baseline: 2.0144x; 1.4299x over previous
//
#include <hip/hip_runtime.h>

#define BSZ   2
#define NBOX  6300
#define NATTR 85
#define NCLS  80
#define CAP   256      // per-(img,class) cap; count ~ Binom(6300,1/160): mean 39, sd 6.3
#define TPB2  512      // nms kernel threads
#define NW    8        // waves per nms block
#define CHUNK 790      // 8*790 = 6320 >= 6300 (per-wave scan chunk)
#define WCAP  128      // per-wave candidate cap (expect ~5; 128 is >>12 sigma)

typedef unsigned long long ull;

static __device__ __forceinline__ ull mask_for(int rem) {
  if (rem <= 0) return 0ull;
  if (rem >= 64) return ~0ull;
  return (1ull << rem) - 1ull;
}

// R3 post-mortem: a device-wide barrier costs ~43-65 us on gfx950 (8 XCD
// non-coherent L2s) no matter how it's implemented (cg grid.sync OR custom
// magic-flag barrier). The kernel BOUNDARY is the cheap device-scope sync.
// So: two kernels, no workspace init, no atomics, no fences.

// Kernel 1 — one wave per box (grid exact, 12600 waves). Lanes load the 85
// attrs coalesced, butterfly-reduce max/argmax over class scores (attrs 5..84,
// first-index tiebreak = jnp.argmax). Lane 0 writes the FINAL output row
// (real row if valid, zeros otherwise) and vcls[box] = valid ? cls : -1.
__global__ __launch_bounds__(256) void prep_kernel(
    const float* __restrict__ x,
    int* __restrict__ vcls,
    float* __restrict__ out) {
  int gid  = blockIdx.x * blockDim.x + threadIdx.x;
  int box  = gid >> 6;                 // grid exact: 12600 waves
  int lane = threadIdx.x & 63;

  const float* p = x + (long)box * NATTR;
  float r0 = p[lane];                                    // attrs 0..63
  float r1 = (lane < NATTR - 64) ? p[64 + lane] : -1.0f; // attrs 64..84

  float c0 = (lane >= 5) ? r0 : -1.0f;
  float v; int vi;
  if (r1 > c0) { v = r1; vi = 64 + lane; }   // equal -> keep lower index c0
  else         { v = c0; vi = lane; }

  for (int off = 32; off > 0; off >>= 1) {   // butterfly max-argmax
    float ov = __shfl_xor(v, off);
    int   oi = __shfl_xor(vi, off);
    if (ov > v || (ov == v && oi < vi)) { v = ov; vi = oi; }
  }

  float cx  = __shfl(r0, 0), cy = __shfl(r0, 1);
  float w   = __shfl(r0, 2), h  = __shfl(r0, 3);
  float obj = __shfl(r0, 4);
  bool valid = (obj > 0.5f) && (v > 0.3f);
  int  img   = box >= NBOX ? 1 : 0;
  int  cls   = vi - 5;

  if (lane == 0) {
    vcls[box] = valid ? cls : -1;
    float4 a, b;
    if (valid) {
      float hw = w * 0.5f, hh = h * 0.5f;    // exact halving; fma-safe
      a = make_float4((float)img, cx - hw, cy - hh, cx + hw);
      b = make_float4(cy + hh, obj, v, (float)cls);
    } else {
      a = make_float4(0.f, 0.f, 0.f, 0.f);
      b = a;
    }
    float4* o = (float4*)(out + (long)box * 8);
    o[0] = a; o[1] = b;
  }
}

// Kernel 2 — one 512-thread block (8 waves) per (img, class). Per-class greedy
// NMS is exactly equivalent to the ref's global greedy loop (suppression
// requires same_cls; invalid boxes never act). Kept rows already final in out;
// this kernel only ZEROES suppressed rows. Scan: 8 waves x 790-chunk ballot
// compaction (R3-verified). Fast path (k<=64, always on this data): whole NMS
// in wave-0 registers via shfl/ds_permute/ballot. LDS fallback for k>64.
__global__ __launch_bounds__(TPB2) void nms_kernel(
    const int* __restrict__ vcls,
    float* out) {
  __shared__ int   wlist[NW][WCAP];
  __shared__ int   wcnt[NW];
  __shared__ int   sbi[CAP];
  // fallback-only arrays (k > 64)
  __shared__ float ssc[CAP];
  __shared__ float px1[CAP], py1[CAP], px2[CAP], py2[CAP];
  __shared__ int   pbi[CAP];

  int bc   = blockIdx.x;
  int img  = bc / NCLS;
  int cls  = bc - img * NCLS;
  int t    = threadIdx.x;
  int lane = t & 63;
  int w    = t >> 6;
  const int* v = vcls + img * NBOX;

  // ---- scan: 8 waves x 790-chunk ballot compaction ----
  int base = w * CHUNK;
  int vals[13];
#pragma unroll
  for (int i = 0; i < 13; i++) {
    int local = i * 64 + lane;
    int idx   = base + local;
    vals[i] = (local < CHUNK && idx < NBOX) ? v[idx] : -1;
  }
  int cnt = 0;
  ull lt = (1ull << lane) - 1ull;
#pragma unroll
  for (int i = 0; i < 13; i++) {
    bool match = (vals[i] == cls);
    ull  m = __ballot(match);
    if (match) {
      int pos = cnt + __popcll(m & lt);
      if (pos < WCAP) wlist[w][pos] = base + i * 64 + lane;
    }
    cnt += __popcll(m);
  }
  if (lane == 0) wcnt[w] = cnt < WCAP ? cnt : WCAP;
  __syncthreads();

  int off = 0, total = 0;
  for (int j = 0; j < NW; j++) {
    int c = wcnt[j];
    if (j < w) off += c;
    total += c;
  }
  int k = total < CAP ? total : CAP;
  if (k == 0) return;                  // uniform

  for (int j = lane; j < wcnt[w]; j += 64) {
    int d = off + j;
    if (d < CAP) sbi[d] = wlist[w][j];  // ascending box-index order
  }
  __syncthreads();

  if (k <= 64) {
    // ================== register fast path (wave 0 only) ==================
    if (w == 0) {
      int j = lane;
      float x1 = 0.f, y1 = 0.f, x2 = 0.f, y2 = 0.f, sc = 0.f;
      int bi = 0;
      if (j < k) {
        bi = sbi[j];
        const float4* o = (const float4*)(out + ((long)img * NBOX + bi) * 8);
        float4 a = o[0], b = o[1];
        x1 = a.y; y1 = a.z; x2 = a.w; y2 = b.x; sc = b.y;
      }
      // rank = stable argsort(-obj, tiebreak: box index asc).
      // All 64 lanes run the loop (no divergence -> shfl well-defined);
      // j>=k lanes get identity rank j (>= k, no collision: sc=0 there).
      int rank = 0;
      for (int i = 0; i < k; i++) {
        float si  = __shfl(sc, i);
        int   bii = __shfl(bi, i);
        rank += (si > sc) || (si == sc && bii < bi);
      }
      if (j >= k) rank = j;

      // scatter to rank order: after this, lane index == rank.
      int r4 = rank << 2;
      x1 = __int_as_float(__builtin_amdgcn_ds_permute(r4, __float_as_int(x1)));
      y1 = __int_as_float(__builtin_amdgcn_ds_permute(r4, __float_as_int(y1)));
      x2 = __int_as_float(__builtin_amdgcn_ds_permute(r4, __float_as_int(x2)));
      y2 = __int_as_float(__builtin_amdgcn_ds_permute(r4, __float_as_int(y2)));
      bi = __builtin_amdgcn_ds_permute(r4, bi);

      float ar = (x2 - x1) * (y2 - y1);   // ref area expression

      // greedy: kept rank r suppresses later ranks with IoU >= 0.4
      ull keep = mask_for(k);
      for (int r = 0; r < k - 1; r++) {
        if (!((keep >> r) & 1ull)) continue;   // uniform skip
        float X1 = __shfl(x1, r), Y1 = __shfl(y1, r);
        float X2 = __shfl(x2, r), Y2 = __shfl(y2, r);
        float AR = __shfl(ar, r);
        float iw = fminf(X2, x2) - fmaxf(X1, x1);
        float ih = fminf(Y2, y2) - fmaxf(Y1, y1);
        iw = fmaxf(iw, 0.0f); ih = fmaxf(ih, 0.0f);
        float inter = iw * ih;
        float iou = inter / (AR + ar - inter + 1e-16f);  // ref assoc + eps
        keep &= ~__ballot(iou >= 0.4f && lane > r);
      }

      // zero only the suppressed rows (kept rows already final from prep)
      if (lane < k && !((keep >> lane) & 1ull)) {
        float4 z = make_float4(0.f, 0.f, 0.f, 0.f);
        float4* o = (float4*)(out + ((long)img * NBOX + bi) * 8);
        o[0] = z; o[1] = z;
      }
    }
    return;
  }

  // ====================== generic LDS fallback (k > 64) ======================
  float bx1 = 0, by1 = 0, bx2 = 0, by2 = 0, bobj = 0;
  int   bidx = 0;
  if (t < k) {
    bidx = sbi[t];
    const float4* o = (const float4*)(out + ((long)img * NBOX + bidx) * 8);
    float4 a = o[0], b = o[1];
    bx1 = a.y; by1 = a.z; bx2 = a.w; by2 = b.x; bobj = b.y;
    ssc[t] = bobj;
  }
  __syncthreads();

  if (t < k) {
    int rank = 0;
    for (int j = 0; j < k; j++) {
      float sj = ssc[j];
      rank += (sj > bobj) || (sj == bobj && sbi[j] < bidx);
    }
    px1[rank] = bx1; py1[rank] = by1;
    px2[rank] = bx2; py2[rank] = by2;
    pbi[rank] = bidx;
  }
  __syncthreads();

  if (w == 0) {
    float mx1[4], my1[4], mx2[4], my2[4], mar[4];
    int   mbi[4];
#pragma unroll
    for (int s = 0; s < 4; s++) {
      int e = s * 64 + lane;
      if (e < k) {
        mx1[s] = px1[e]; my1[s] = py1[e];
        mx2[s] = px2[e]; my2[s] = py2[e];
        mbi[s] = pbi[e];
        mar[s] = (mx2[s] - mx1[s]) * (my2[s] - my1[s]);
      } else {
        mx1[s] = 0; my1[s] = 0; mx2[s] = 0; my2[s] = 0; mar[s] = 0; mbi[s] = 0;
      }
    }
    ull km0 = mask_for(k);
    ull km1 = mask_for(k - 64);
    ull km2 = mask_for(k - 128);
    ull km3 = mask_for(k - 192);

    for (int r = 0; r < k - 1; r++) {
      ull cur = (r < 64) ? km0 : (r < 128) ? km1 : (r < 192) ? km2 : km3;
      if (!((cur >> (r & 63)) & 1ull)) continue;
      float X1 = px1[r], Y1 = py1[r], X2 = px2[r], Y2 = py2[r];
      float ar = (X2 - X1) * (Y2 - Y1);
      {
        int e = lane;
        float iw = fminf(X2, mx2[0]) - fmaxf(X1, mx1[0]);
        float ih = fminf(Y2, my2[0]) - fmaxf(Y1, my1[0]);
        iw = fmaxf(iw, 0.0f); ih = fmaxf(ih, 0.0f);
        float inter = iw * ih;
        float iou = inter / (ar + mar[0] - inter + 1e-16f);
        km0 &= ~__ballot(iou >= 0.4f && e > r && e < k);
      }
      if (k > 64) {
        int e = 64 + lane;
        float iw = fminf(X2, mx2[1]) - fmaxf(X1, mx1[1]);
        float ih = fminf(Y2, my2[1]) - fmaxf(Y1, my1[1]);
        iw = fmaxf(iw, 0.0f); ih = fmaxf(ih, 0.0f);
        float inter = iw * ih;
        float iou = inter / (ar + mar[1] - inter + 1e-16f);
        km1 &= ~__ballot(iou >= 0.4f && e > r && e < k);
      }
      if (k > 128) {
        int e = 128 + lane;
        float iw = fminf(X2, mx2[2]) - fmaxf(X1, mx1[2]);
        float ih = fminf(Y2, my2[2]) - fmaxf(Y1, my1[2]);
        iw = fmaxf(iw, 0.0f); ih = fmaxf(ih, 0.0f);
        float inter = iw * ih;
        float iou = inter / (ar + mar[2] - inter + 1e-16f);
        km2 &= ~__ballot(iou >= 0.4f && e > r && e < k);
      }
      if (k > 192) {
        int e = 192 + lane;
        float iw = fminf(X2, mx2[3]) - fmaxf(X1, mx1[3]);
        float ih = fminf(Y2, my2[3]) - fmaxf(Y1, my1[3]);
        iw = fmaxf(iw, 0.0f); ih = fmaxf(ih, 0.0f);
        float inter = iw * ih;
        float iou = inter / (ar + mar[3] - inter + 1e-16f);
        km3 &= ~__ballot(iou >= 0.4f && e > r && e < k);
      }
    }

    float4 z = make_float4(0.f, 0.f, 0.f, 0.f);
#pragma unroll
    for (int s = 0; s < 4; s++) {
      ull kms = (s == 0) ? km0 : (s == 1) ? km1 : (s == 2) ? km2 : km3;
      int e = s * 64 + lane;
      if (e < k && !((kms >> lane) & 1ull)) {
        float4* o = (float4*)(out + ((long)img * NBOX + mbi[s]) * 8);
        o[0] = z; o[1] = z;
      }
    }
  }
}

extern "C" void kernel_launch(void* const* d_in, const int* in_sizes, int n_in,
                              void* d_out, int out_size, void* d_ws, size_t ws_size,
                              hipStream_t stream) {
  const float* x = (const float*)d_in[0];
  float* out = (float*)d_out;
  int* vcls = (int*)d_ws;   // [BSZ*NBOX]

  prep_kernel<<<(BSZ * NBOX * 64) / 256, 256, 0, stream>>>(x, vcls, out);
  nms_kernel<<<BSZ * NCLS, TPB2, 0, stream>>>(vcls, out);
}